// Round 1
// baseline (1570.713 us; speedup 1.0000x reference)
//
#include <hip/hip_runtime.h>

#define BATCH 256
#define PIX 65536

typedef short bf16x8 __attribute__((ext_vector_type(8)));
typedef float f32x4 __attribute__((ext_vector_type(4)));

__device__ __forceinline__ unsigned short bf16rne(float f) {
  unsigned u = __float_as_uint(f);
  u += 0x7FFFu + ((u >> 16) & 1u);
  return (unsigned short)(u >> 16);
}

__device__ __forceinline__ float tanh_fast(float x) {
  float e = __expf(2.0f * x);
  return 1.0f - 2.0f / (e + 1.0f);
}

// ---------------- x0 = concat(embed[labels], noise) ----------------
__global__ void k_build_x0(const float* __restrict__ noise, const int* __restrict__ labels,
                           const float* __restrict__ embed, float* __restrict__ x0) {
  int row = blockIdx.x, t = threadIdx.x;
  if (t < 110) {
    float v = (t < 10) ? embed[labels[row] * 10 + t] : noise[row * 100 + (t - 10)];
    x0[row * 110 + t] = v;
  }
}

// ---------------- small layer: h = x@W+b; BN(batch stats, eps=0.8); LeakyReLU(0.2)
// one block per output feature j; thread i = batch row.
__global__ __launch_bounds__(256) void k_layer(
    const float* __restrict__ xin, const float* __restrict__ W,
    const float* __restrict__ bias, const float* __restrict__ gam,
    const float* __restrict__ bet, float* __restrict__ xout,
    unsigned short* __restrict__ afrag, int K, int N) {
  int j = blockIdx.x, i = threadIdx.x;
  float a0 = 0.f, a1 = 0.f, a2 = 0.f, a3 = 0.f;
  int k = 0;
  for (; k + 4 <= K; k += 4) {
    a0 = fmaf(xin[i * K + k + 0], W[(k + 0) * N + j], a0);
    a1 = fmaf(xin[i * K + k + 1], W[(k + 1) * N + j], a1);
    a2 = fmaf(xin[i * K + k + 2], W[(k + 2) * N + j], a2);
    a3 = fmaf(xin[i * K + k + 3], W[(k + 3) * N + j], a3);
  }
  for (; k < K; ++k) a0 = fmaf(xin[i * K + k], W[k * N + j], a0);
  float h = a0 + a1 + a2 + a3 + bias[j];

  __shared__ float rs[256], rq[256];
  rs[i] = h; rq[i] = h * h;
  __syncthreads();
  for (int s = 128; s > 0; s >>= 1) {
    if (i < s) { rs[i] += rs[i + s]; rq[i] += rq[i + s]; }
    __syncthreads();
  }
  float mu = rs[0] * (1.0f / 256.0f);
  float var = rq[0] * (1.0f / 256.0f) - mu * mu;
  float y = (h - mu) * rsqrtf(var + 0.8f) * gam[j] + bet[j];
  y = (y >= 0.0f) ? y : 0.2f * y;
  if (xout) xout[i * N + j] = y;
  if (afrag) {
    // fragment-ordered bf16 for GEMM A: elem((kc,mt,lane),e) = A[mt*16+r][kc*32+8*g+e]
    int kc = j >> 5, kin = j & 31, g = kin >> 3, e = kin & 7;
    int mt = i >> 4, r = i & 15;
    afrag[(size_t)(((kc * 16 + mt) * 64) + (r + (g << 4))) * 8 + e] = bf16rne(y);
  }
}

// ---------------- GEMM5: img = tanh(x4 @ W5 + b5), bf16 MFMA 16x16x32 ----------------
// grid: 1024 blocks (64 N-cols each); block 256 = 4 waves, each wave owns 64 M-rows.
__global__ __launch_bounds__(256) void k_gemm5(
    const unsigned short* __restrict__ A, const float* __restrict__ W5,
    const float* __restrict__ b5, float* __restrict__ img) {
  __shared__ unsigned short Bs[4096];  // [kcc(2)][nt(4)][lane(64)][e(8)] bf16, 8KB
  const int n0 = blockIdx.x << 6;
  const int tid = threadIdx.x;
  const int w = tid >> 6, lane = tid & 63;
  f32x4 acc[4][4];
#pragma unroll
  for (int m = 0; m < 4; ++m)
#pragma unroll
    for (int n = 0; n < 4; ++n) acc[m][n] = (f32x4){0.f, 0.f, 0.f, 0.f};

  for (int cc = 0; cc < 16; ++cc) {  // K chunks of 64
    __syncthreads();
    // stage B chunk: thread (w,lane): col=lane, k = cc*64 + half*32 + w*8 + q
#pragma unroll
    for (int half = 0; half < 2; ++half) {
      int kk = cc * 64 + half * 32 + w * 8;
      bf16x8 pk;
#pragma unroll
      for (int q = 0; q < 8; ++q) {
        float v = W5[(size_t)(kk + q) * PIX + n0 + lane];
        pk[q] = (short)bf16rne(v);
      }
      int dst = ((half * 4 + (lane >> 4)) * 64 + ((lane & 15) + (w << 4))) * 8;
      *(bf16x8*)&Bs[dst] = pk;
    }
    __syncthreads();
#pragma unroll
    for (int kcc = 0; kcc < 2; ++kcc) {
      int kc = cc * 2 + kcc;
      bf16x8 a[4], bv[4];
#pragma unroll
      for (int m = 0; m < 4; ++m)
        a[m] = *(const bf16x8*)&A[(size_t)((kc * 16 + (w * 4 + m)) * 64 + lane) * 8];
#pragma unroll
      for (int n = 0; n < 4; ++n)
        bv[n] = *(const bf16x8*)&Bs[((kcc * 4 + n) * 64 + lane) * 8];
#pragma unroll
      for (int m = 0; m < 4; ++m)
#pragma unroll
        for (int n = 0; n < 4; ++n)
          acc[m][n] = __builtin_amdgcn_mfma_f32_16x16x32_bf16(a[m], bv[n], acc[m][n], 0, 0, 0);
    }
  }
  // epilogue: C/D layout col=lane&15, row=(lane>>4)*4+reg (m89-verified)
#pragma unroll
  for (int m = 0; m < 4; ++m) {
    int rb = (w << 6) + (m << 4) + ((lane >> 4) << 2);
#pragma unroll
    for (int n = 0; n < 4; ++n) {
      int col = n0 + (n << 4) + (lane & 15);
      float bb = b5[col];
#pragma unroll
      for (int r = 0; r < 4; ++r) {
        float h = acc[m][n][r] + bb;
        img[(size_t)(rb + r) * PIX + col] = tanh_fast(h);
      }
    }
  }
}

// ---------------- radix sort passes: 2 x 11-bit digits on top-22 key bits ----------------
// one block per row (65536 elems), 8 waves, wave owns contiguous 8192 chunk (stable).
__device__ __forceinline__ unsigned long long match11(unsigned d) {
  unsigned long long m = ~0ull;
#pragma unroll
  for (int b = 0; b < 11; ++b) {
    unsigned long long bal = __ballot((d >> b) & 1u);
    m &= ((d >> b) & 1u) ? bal : ~bal;
  }
  return m;
}

template <int MODE>  // 0: p pass1, 1: p pass2, 2: g pass1, 3: g pass2 (+gather)
__device__ __forceinline__ void loadrec(const void* in, size_t gi, int e, unsigned& key, unsigned& pay) {
  if constexpr (MODE == 0 || MODE == 1) {
    key = ((const unsigned*)in)[gi];  // p >= 0: raw bits are order-preserving
    pay = 0;
  } else if constexpr (MODE == 2) {
    unsigned u = ((const unsigned*)in)[gi];
    key = u ^ ((u >> 31) ? 0xFFFFFFFFu : 0x80000000u);  // signed-float ordered key
    pay = (unsigned)e;
  } else {
    uint2 r = ((const uint2*)in)[gi];
    key = r.x; pay = r.y;
  }
}

template <int MODE>
__device__ __forceinline__ unsigned getdig(unsigned key) {
  if constexpr (MODE == 0 || MODE == 2) return (key >> 10) & 2047u;  // pass 1: bits 10..20
  else return key >> 21;                                             // pass 2: bits 21..31
}

template <int MODE>
__global__ __launch_bounds__(512) void k_sort_pass(
    const void* __restrict__ in, void* __restrict__ out,
    const unsigned* __restrict__ sortp, float* __restrict__ outq) {
  __shared__ unsigned hist[8 * 2048];
  __shared__ unsigned tot[2048];
  __shared__ unsigned wsum[8];
  const int row = blockIdx.x;
  const int tid = threadIdx.x;
  const int w = tid >> 6, lane = tid & 63;
  const size_t rbase = (size_t)row << 16;
  const int cbase = w << 13;
  const unsigned long long lmask = (1ull << lane) - 1ull;

  for (int i = tid; i < 8 * 2048; i += 512) hist[i] = 0;
  __syncthreads();

  // phase A: per-wave digit histogram (ballot-match, leader-update, no atomics)
  for (int s = 0; s < 128; ++s) {
    int e = cbase + (s << 6) + lane;
    unsigned key, pay;
    loadrec<MODE>(in, rbase + e, e, key, pay);
    unsigned d = getdig<MODE>(key);
    unsigned long long m = match11(d);
    int rk = __popcll(m & lmask);
    if (rk == 0) hist[(w << 11) + d] += (unsigned)__popcll(m);
  }
  __syncthreads();

  // per-digit exclusive prefix over waves + digit totals
#pragma unroll
  for (int q = 0; q < 4; ++q) {
    int d = (tid << 2) + q;
    unsigned s = 0;
#pragma unroll
    for (int ww = 0; ww < 8; ++ww) {
      unsigned t = hist[(ww << 11) + d];
      hist[(ww << 11) + d] = s;
      s += t;
    }
    tot[d] = s;
  }
  __syncthreads();

  // block exclusive scan over 2048 digit totals (thread owns digits 4t..4t+3)
  unsigned a0 = tot[(tid << 2)], a1 = tot[(tid << 2) + 1], a2 = tot[(tid << 2) + 2], a3 = tot[(tid << 2) + 3];
  unsigned tsum = a0 + a1 + a2 + a3;
  unsigned sc = tsum;
#pragma unroll
  for (int o = 1; o < 64; o <<= 1) {
    unsigned v = __shfl_up(sc, o);
    if (lane >= o) sc += v;
  }
  if (lane == 63) wsum[w] = sc;
  unsigned excl = sc - tsum;
  __syncthreads();
  unsigned wb = 0;
  for (int ww = 0; ww < w; ++ww) wb += wsum[ww];
  unsigned b0 = wb + excl;
  unsigned bb[4] = {b0, b0 + a0, b0 + a0 + a1, b0 + a0 + a1 + a2};
  for (int ww = 0; ww < 8; ++ww) {
#pragma unroll
    for (int q = 0; q < 4; ++q) hist[(ww << 11) + (tid << 2) + q] += bb[q];
  }
  __syncthreads();

  // phase B: stable scatter (per-wave private running counters)
  for (int s = 0; s < 128; ++s) {
    int e = cbase + (s << 6) + lane;
    unsigned key, pay;
    loadrec<MODE>(in, rbase + e, e, key, pay);
    unsigned d = getdig<MODE>(key);
    unsigned long long m = match11(d);
    int rk = __popcll(m & lmask);
    unsigned base = hist[(w << 11) + d];
    unsigned pos = base + (unsigned)rk;
    if (rk == 0) hist[(w << 11) + d] = base + (unsigned)__popcll(m);
    if constexpr (MODE == 0) {
      ((unsigned*)out)[rbase + pos] = key;
    } else if constexpr (MODE == 1) {
      ((unsigned*)out)[rbase + pos] = key;
    } else if constexpr (MODE == 2) {
      ((uint2*)out)[rbase + pos] = make_uint2(key, (unsigned)e);
    } else {
      outq[rbase + pay] = __uint_as_float(sortp[rbase + pos]);
    }
  }
}

// ---------------- launch ----------------
extern "C" void kernel_launch(void* const* d_in, const int* in_sizes, int n_in,
                              void* d_out, int out_size, void* d_ws, size_t ws_size,
                              hipStream_t stream) {
  (void)in_sizes; (void)n_in; (void)out_size; (void)ws_size;
  const float* noise = (const float*)d_in[0];
  const float* rimg  = (const float*)d_in[1];
  const int* labels  = (const int*)d_in[2];
  const float* embed = (const float*)d_in[3];
  const float* W1 = (const float*)d_in[4];  const float* b1 = (const float*)d_in[5];
  const float* g1 = (const float*)d_in[6];  const float* be1 = (const float*)d_in[7];
  const float* W2 = (const float*)d_in[8];  const float* b2 = (const float*)d_in[9];
  const float* g2 = (const float*)d_in[10]; const float* be2 = (const float*)d_in[11];
  const float* W3 = (const float*)d_in[12]; const float* b3 = (const float*)d_in[13];
  const float* g3 = (const float*)d_in[14]; const float* be3 = (const float*)d_in[15];
  const float* W4 = (const float*)d_in[16]; const float* b4 = (const float*)d_in[17];
  const float* g4 = (const float*)d_in[18]; const float* be4 = (const float*)d_in[19];
  const float* W5 = (const float*)d_in[20]; const float* b5 = (const float*)d_in[21];

  float* outq = (float*)d_out;                       // img_quantized
  float* img  = (float*)d_out + (size_t)BATCH * PIX; // img

  char* ws = (char*)d_ws;
  unsigned* sortp = (unsigned*)ws;                          // [0, 64MB): sorted p (u32 bits)
  void* tmp = (void*)(ws + (size_t)64 * 1024 * 1024);       // [64MB, 192MB): radix tmp
  char* small = ws + (size_t)192 * 1024 * 1024;
  float* x0 = (float*)small;
  float* x1 = (float*)(small + (1 << 20));
  float* x2 = (float*)(small + (2 << 20));
  float* x3 = (float*)(small + (3 << 20));
  float* x4f = (float*)(small + (4 << 20));
  unsigned short* x4b = (unsigned short*)(small + (5 << 20));

  k_build_x0<<<256, 128, 0, stream>>>(noise, labels, embed, x0);
  k_layer<<<128, 256, 0, stream>>>(x0, W1, b1, g1, be1, x1, nullptr, 110, 128);
  k_layer<<<256, 256, 0, stream>>>(x1, W2, b2, g2, be2, x2, nullptr, 128, 256);
  k_layer<<<512, 256, 0, stream>>>(x2, W3, b3, g3, be3, x3, nullptr, 256, 512);
  k_layer<<<1024, 256, 0, stream>>>(x3, W4, b4, g4, be4, x4f, x4b, 512, 1024);
  k_gemm5<<<1024, 256, 0, stream>>>(x4b, W5, b5, img);

  k_sort_pass<0><<<256, 512, 0, stream>>>(rimg, tmp, nullptr, nullptr);
  k_sort_pass<1><<<256, 512, 0, stream>>>(tmp, sortp, nullptr, nullptr);
  k_sort_pass<2><<<256, 512, 0, stream>>>(img, tmp, nullptr, nullptr);
  k_sort_pass<3><<<256, 512, 0, stream>>>(tmp, nullptr, sortp, outq);
}

// Round 2
// 1205.891 us; speedup vs baseline: 1.3025x; 1.3025x over previous
//
#include <hip/hip_runtime.h>

#define BATCH 256
#define PIX 65536
#define NB 2048      // 11-bit digits
#define CHUNK 4096
#define CH 16        // chunks per row (CH*CHUNK == PIX)

typedef short bf16x8 __attribute__((ext_vector_type(8)));
typedef float f32x4 __attribute__((ext_vector_type(4)));
typedef unsigned int u32;
typedef unsigned short u16;
typedef unsigned long long u64;

__device__ __forceinline__ unsigned short bf16rne(float f) {
  unsigned u = __float_as_uint(f);
  u += 0x7FFFu + ((u >> 16) & 1u);
  return (unsigned short)(u >> 16);
}

__device__ __forceinline__ float tanh_fast(float x) {
  float e = __expf(2.0f * x);
  return 1.0f - 2.0f / (e + 1.0f);
}

// ---------------- x0 = concat(embed[labels], noise) ----------------
__global__ void k_build_x0(const float* __restrict__ noise, const int* __restrict__ labels,
                           const float* __restrict__ embed, float* __restrict__ x0) {
  int row = blockIdx.x, t = threadIdx.x;
  if (t < 110) {
    float v = (t < 10) ? embed[labels[row] * 10 + t] : noise[row * 100 + (t - 10)];
    x0[row * 110 + t] = v;
  }
}

// ---------------- small layer: h = x@W+b; BN(batch stats, eps=0.8); LeakyReLU(0.2)
__global__ __launch_bounds__(256) void k_layer(
    const float* __restrict__ xin, const float* __restrict__ W,
    const float* __restrict__ bias, const float* __restrict__ gam,
    const float* __restrict__ bet, float* __restrict__ xout,
    unsigned short* __restrict__ afrag, int K, int N) {
  int j = blockIdx.x, i = threadIdx.x;
  float a0 = 0.f, a1 = 0.f, a2 = 0.f, a3 = 0.f;
  int k = 0;
  for (; k + 4 <= K; k += 4) {
    a0 = fmaf(xin[i * K + k + 0], W[(k + 0) * N + j], a0);
    a1 = fmaf(xin[i * K + k + 1], W[(k + 1) * N + j], a1);
    a2 = fmaf(xin[i * K + k + 2], W[(k + 2) * N + j], a2);
    a3 = fmaf(xin[i * K + k + 3], W[(k + 3) * N + j], a3);
  }
  for (; k < K; ++k) a0 = fmaf(xin[i * K + k], W[k * N + j], a0);
  float h = a0 + a1 + a2 + a3 + bias[j];

  __shared__ float rs[256], rq[256];
  rs[i] = h; rq[i] = h * h;
  __syncthreads();
  for (int s = 128; s > 0; s >>= 1) {
    if (i < s) { rs[i] += rs[i + s]; rq[i] += rq[i + s]; }
    __syncthreads();
  }
  float mu = rs[0] * (1.0f / 256.0f);
  float var = rq[0] * (1.0f / 256.0f) - mu * mu;
  float y = (h - mu) * rsqrtf(var + 0.8f) * gam[j] + bet[j];
  y = (y >= 0.0f) ? y : 0.2f * y;
  if (xout) xout[i * N + j] = y;
  if (afrag) {
    int kc = j >> 5, kin = j & 31, g = kin >> 3, e = kin & 7;
    int mt = i >> 4, r = i & 15;
    afrag[(size_t)(((kc * 16 + mt) * 64) + (r + (g << 4))) * 8 + e] = bf16rne(y);
  }
}

// ---------------- GEMM5: img = tanh(x4 @ W5 + b5), bf16 MFMA 16x16x32 ----------------
__global__ __launch_bounds__(256) void k_gemm5(
    const unsigned short* __restrict__ A, const float* __restrict__ W5,
    const float* __restrict__ b5, float* __restrict__ img) {
  __shared__ unsigned short Bs[4096];
  const int n0 = blockIdx.x << 6;
  const int tid = threadIdx.x;
  const int w = tid >> 6, lane = tid & 63;
  f32x4 acc[4][4];
#pragma unroll
  for (int m = 0; m < 4; ++m)
#pragma unroll
    for (int n = 0; n < 4; ++n) acc[m][n] = (f32x4){0.f, 0.f, 0.f, 0.f};

  for (int cc = 0; cc < 16; ++cc) {
    __syncthreads();
#pragma unroll
    for (int half = 0; half < 2; ++half) {
      int kk = cc * 64 + half * 32 + w * 8;
      bf16x8 pk;
#pragma unroll
      for (int q = 0; q < 8; ++q) {
        float v = W5[(size_t)(kk + q) * PIX + n0 + lane];
        pk[q] = (short)bf16rne(v);
      }
      int dst = ((half * 4 + (lane >> 4)) * 64 + ((lane & 15) + (w << 4))) * 8;
      *(bf16x8*)&Bs[dst] = pk;
    }
    __syncthreads();
#pragma unroll
    for (int kcc = 0; kcc < 2; ++kcc) {
      int kc = cc * 2 + kcc;
      bf16x8 a[4], bv[4];
#pragma unroll
      for (int m = 0; m < 4; ++m)
        a[m] = *(const bf16x8*)&A[(size_t)((kc * 16 + (w * 4 + m)) * 64 + lane) * 8];
#pragma unroll
      for (int n = 0; n < 4; ++n)
        bv[n] = *(const bf16x8*)&Bs[((kcc * 4 + n) * 64 + lane) * 8];
#pragma unroll
      for (int m = 0; m < 4; ++m)
#pragma unroll
        for (int n = 0; n < 4; ++n)
          acc[m][n] = __builtin_amdgcn_mfma_f32_16x16x32_bf16(a[m], bv[n], acc[m][n], 0, 0, 0);
    }
  }
#pragma unroll
  for (int m = 0; m < 4; ++m) {
    int rb = (w << 6) + (m << 4) + ((lane >> 4) << 2);
#pragma unroll
    for (int n = 0; n < 4; ++n) {
      int col = n0 + (n << 4) + (lane & 15);
      float bb = b5[col];
#pragma unroll
      for (int r = 0; r < 4; ++r) {
        float h = acc[m][n][r] + bb;
        img[(size_t)(rb + r) * PIX + col] = tanh_fast(h);
      }
    }
  }
}

// ================= multi-block LSD radix sort (2 x 11-bit passes) =================
// MODE 0: p pass1 (raw key, lo digit)   MODE 1: p pass2 (raw key, hi digit)
// MODE 2: g pass1 (flip key, lo digit)  MODE 3: g pass2 (raw key, hi digit, +gather)

__device__ __forceinline__ u64 match11(u32 d) {
  u64 m = ~0ull;
#pragma unroll
  for (int b = 0; b < 11; ++b) {
    u64 bal = __ballot((d >> b) & 1u);
    m &= ((d >> b) & 1u) ? bal : ~bal;
  }
  return m;
}

template <int MODE>
__device__ __forceinline__ u32 loadkey(const u32* __restrict__ in, size_t gi) {
  u32 u = in[gi];
  if constexpr (MODE == 2) u = u ^ ((u >> 31) ? 0xFFFFFFFFu : 0x80000000u);
  return u;
}

template <int MODE>
__device__ __forceinline__ u32 getdig(u32 key) {
  if constexpr (MODE == 0 || MODE == 2) return (key >> 10) & 2047u;
  else return key >> 21;
}

// ---- kernel H: per-chunk digit histogram; grid 4096 (row*CH+chunk), block 256 ----
template <int MODE>
__global__ __launch_bounds__(256) void k_hist(const u32* __restrict__ in, u16* __restrict__ hist) {
  __shared__ u16 wh[4][NB];
  const int bid = blockIdx.x, tid = threadIdx.x;
  const int w = tid >> 6, lane = tid & 63;
  u32* z = (u32*)wh;
  for (int i = tid; i < 4 * NB / 2; i += 256) z[i] = 0;
  __syncthreads();
  const size_t base = (size_t)bid * CHUNK;
  const u64 lmask = (1ull << lane) - 1ull;
#pragma unroll 4
  for (int it = 0; it < 16; ++it) {
    u32 key = loadkey<MODE>(in, base + w * 1024 + it * 64 + lane);
    u32 d = getdig<MODE>(key);
    u64 m = match11(d);
    if (!(m & lmask)) wh[w][d] += (u16)__popcll(m);
  }
  __syncthreads();
#pragma unroll
  for (int q = 0; q < 8; ++q) {
    int d = q * 256 + tid;
    hist[(size_t)bid * NB + d] = (u16)(wh[0][d] + wh[1][d] + wh[2][d] + wh[3][d]);
  }
}

// ---- kernel S: per-row scan over (chunk, digit) -> global u16 bases; grid 256, block 512 ----
__global__ __launch_bounds__(512) void k_scan(u16* __restrict__ hist) {
  __shared__ u16 h[CH * NB];   // 64KB
  __shared__ u32 wsum[8];
  const int row = blockIdx.x, tid = threadIdx.x;
  const int w = tid >> 6, lane = tid & 63;
  const size_t gb = (size_t)row * CH * NB;
  for (int i = tid; i < CH * NB; i += 512) h[i] = hist[gb + i];
  __syncthreads();
  u32 a[4];
#pragma unroll
  for (int q = 0; q < 4; ++q) {
    int d = tid * 4 + q;
    u32 s = 0;
#pragma unroll
    for (int c = 0; c < CH; ++c) {
      u32 v = h[c * NB + d];
      h[c * NB + d] = (u16)s;
      s += v;
    }
    a[q] = s;
  }
  u32 tsum = a[0] + a[1] + a[2] + a[3];
  u32 sc = tsum;
#pragma unroll
  for (int o = 1; o < 64; o <<= 1) {
    u32 v = __shfl_up(sc, o);
    if (lane >= o) sc += v;
  }
  if (lane == 63) wsum[w] = sc;
  u32 excl = sc - tsum;
  __syncthreads();
  u32 wb = 0;
  for (int ww = 0; ww < w; ++ww) wb += wsum[ww];
  u32 b0 = wb + excl;
  u32 bb[4] = {b0, b0 + a[0], b0 + a[0] + a[1], b0 + a[0] + a[1] + a[2]};
#pragma unroll
  for (int q = 0; q < 4; ++q) {
    int d = tid * 4 + q;
#pragma unroll
    for (int c = 0; c < CH; ++c) h[c * NB + d] = (u16)(h[c * NB + d] + bb[q]);
  }
  __syncthreads();
  for (int i = tid; i < CH * NB; i += 512) hist[gb + i] = h[i];
}

// ---- kernel X: local stable sort in LDS + clustered global scatter; grid 4096, block 256 ----
template <int MODE>
__global__ __launch_bounds__(256) void k_scatter(
    const u32* __restrict__ in, const u16* __restrict__ inIdx,
    const u16* __restrict__ hist, u32* __restrict__ outk, u16* __restrict__ outIdx,
    const u32* __restrict__ sortp, float* __restrict__ outq) {
  __shared__ u16 wh[4][NB];   // 16KB
  __shared__ u16 lst[NB];     // 4KB
  __shared__ u16 gbs[NB];     // 4KB
  __shared__ u32 kbuf[CHUNK]; // 16KB
  __shared__ u16 ibuf[(MODE >= 2) ? CHUNK : 64];
  __shared__ u32 wsum[4];
  const int bid = blockIdx.x, tid = threadIdx.x;
  const int w = tid >> 6, lane = tid & 63;
  const size_t base = (size_t)bid * CHUNK;
  const u32 rowbase = (u32)(bid >> 4) << 16;
  {
    u32* z = (u32*)wh;
    for (int i = tid; i < 4 * NB / 2; i += 256) z[i] = 0;
  }
#pragma unroll
  for (int q = 0; q < 8; ++q) {
    int d = q * 256 + tid;
    gbs[d] = hist[(size_t)bid * NB + d];
  }
  __syncthreads();
  const u64 lmask = (1ull << lane) - 1ull;
  u32 keys[16];
  u16 pays[16];
  // phase A: per-wave digit counts (keys cached in registers)
#pragma unroll 4
  for (int it = 0; it < 16; ++it) {
    size_t gi = base + w * 1024 + it * 64 + lane;
    keys[it] = loadkey<MODE>(in, gi);
    if constexpr (MODE == 3) pays[it] = inIdx[gi];
    u32 d = getdig<MODE>(keys[it]);
    u64 m = match11(d);
    if (!(m & lmask)) wh[w][d] += (u16)__popcll(m);
  }
  __syncthreads();
  // scan: wave-exclusive per digit + block digit-order exclusive starts
  u32 a[8];
  u32 t8 = 0;
#pragma unroll
  for (int q = 0; q < 8; ++q) {
    int d = tid * 8 + q;
    u32 s = 0;
#pragma unroll
    for (int ww = 0; ww < 4; ++ww) {
      u32 v = wh[ww][d];
      wh[ww][d] = (u16)s;
      s += v;
    }
    a[q] = s;
    t8 += s;
  }
  u32 sc = t8;
#pragma unroll
  for (int o = 1; o < 64; o <<= 1) {
    u32 v = __shfl_up(sc, o);
    if (lane >= o) sc += v;
  }
  if (lane == 63) wsum[w] = sc;
  u32 excl = sc - t8;
  __syncthreads();
  u32 wb = 0;
  for (int ww = 0; ww < w; ++ww) wb += wsum[ww];
  u32 run = wb + excl;
#pragma unroll
  for (int q = 0; q < 8; ++q) {
    int d = tid * 8 + q;
    lst[d] = (u16)run;
    run += a[q];
  }
  __syncthreads();
  // phase B: stable rank -> LDS reorder
#pragma unroll 4
  for (int it = 0; it < 16; ++it) {
    u32 key = keys[it];
    u32 d = getdig<MODE>(key);
    u64 m = match11(d);
    int rk = __popcll(m & lmask);
    u32 slot = (u32)lst[d] + (u32)wh[w][d] + (u32)rk;
    if (!rk) wh[w][d] += (u16)__popcll(m);
    kbuf[slot] = key;
    if constexpr (MODE == 2) ibuf[slot] = (u16)((bid & 15) * CHUNK + w * 1024 + it * 64 + lane);
    if constexpr (MODE == 3) ibuf[slot] = pays[it];
  }
  __syncthreads();
  // write-out: consecutive LDS slots with equal digit -> consecutive global addresses
  for (int i = tid; i < CHUNK; i += 256) {
    u32 k = kbuf[i];
    u32 d = getdig<MODE>(k);
    u32 pos16 = (u32)(u16)((u32)gbs[d] + (u32)i - (u32)lst[d]);
    u32 pos = rowbase + pos16;
    if constexpr (MODE == 0 || MODE == 1) {
      outk[pos] = k;
    } else if constexpr (MODE == 2) {
      outk[pos] = k;
      outIdx[pos] = ibuf[i];
    } else {
      u32 v = sortp[pos];
      outq[rowbase + (u32)ibuf[i]] = __uint_as_float(v);
    }
  }
}

// ---------------- launch ----------------
extern "C" void kernel_launch(void* const* d_in, const int* in_sizes, int n_in,
                              void* d_out, int out_size, void* d_ws, size_t ws_size,
                              hipStream_t stream) {
  (void)in_sizes; (void)n_in; (void)out_size; (void)ws_size;
  const float* noise = (const float*)d_in[0];
  const float* rimg  = (const float*)d_in[1];
  const int* labels  = (const int*)d_in[2];
  const float* embed = (const float*)d_in[3];
  const float* W1 = (const float*)d_in[4];  const float* b1 = (const float*)d_in[5];
  const float* g1 = (const float*)d_in[6];  const float* be1 = (const float*)d_in[7];
  const float* W2 = (const float*)d_in[8];  const float* b2 = (const float*)d_in[9];
  const float* g2 = (const float*)d_in[10]; const float* be2 = (const float*)d_in[11];
  const float* W3 = (const float*)d_in[12]; const float* b3 = (const float*)d_in[13];
  const float* g3 = (const float*)d_in[14]; const float* be3 = (const float*)d_in[15];
  const float* W4 = (const float*)d_in[16]; const float* b4 = (const float*)d_in[17];
  const float* g4 = (const float*)d_in[18]; const float* be4 = (const float*)d_in[19];
  const float* W5 = (const float*)d_in[20]; const float* b5 = (const float*)d_in[21];

  float* outq = (float*)d_out;                        // img_quantized
  float* img  = (float*)d_out + (size_t)BATCH * PIX;  // img

  char* ws = (char*)d_ws;
  u32* tmpk  = (u32*)ws;                                   // [0,   64M)
  u16* tmpi  = (u16*)(ws + (size_t)64 * 1024 * 1024);      // [64M, 96M)
  u32* sortp = (u32*)(ws + (size_t)96 * 1024 * 1024);      // [96M, 160M)
  u16* histg = (u16*)(ws + (size_t)160 * 1024 * 1024);     // [160M,176M)
  char* small = ws + (size_t)176 * 1024 * 1024;
  float* x0 = (float*)small;
  float* x1 = (float*)(small + (1 << 20));
  float* x2 = (float*)(small + (2 << 20));
  float* x3 = (float*)(small + (3 << 20));
  float* x4f = (float*)(small + (4 << 20));
  unsigned short* x4b = (unsigned short*)(small + (5 << 20));

  k_build_x0<<<256, 128, 0, stream>>>(noise, labels, embed, x0);
  k_layer<<<128, 256, 0, stream>>>(x0, W1, b1, g1, be1, x1, nullptr, 110, 128);
  k_layer<<<256, 256, 0, stream>>>(x1, W2, b2, g2, be2, x2, nullptr, 128, 256);
  k_layer<<<512, 256, 0, stream>>>(x2, W3, b3, g3, be3, x3, nullptr, 256, 512);
  k_layer<<<1024, 256, 0, stream>>>(x3, W4, b4, g4, be4, x4f, x4b, 512, 1024);
  k_gemm5<<<1024, 256, 0, stream>>>(x4b, W5, b5, img);

  const int GH = BATCH * CH;  // 4096 blocks
  // ---- p chain: rimg -> tmpk -> sortp ----
  k_hist<0><<<GH, 256, 0, stream>>>((const u32*)rimg, histg);
  k_scan<<<BATCH, 512, 0, stream>>>(histg);
  k_scatter<0><<<GH, 256, 0, stream>>>((const u32*)rimg, nullptr, histg, tmpk, nullptr, nullptr, nullptr);
  k_hist<1><<<GH, 256, 0, stream>>>(tmpk, histg);
  k_scan<<<BATCH, 512, 0, stream>>>(histg);
  k_scatter<1><<<GH, 256, 0, stream>>>(tmpk, nullptr, histg, sortp, nullptr, nullptr, nullptr);
  // ---- g chain: img -> (tmpk,tmpi) -> gather ----
  k_hist<2><<<GH, 256, 0, stream>>>((const u32*)img, histg);
  k_scan<<<BATCH, 512, 0, stream>>>(histg);
  k_scatter<2><<<GH, 256, 0, stream>>>((const u32*)img, nullptr, histg, tmpk, tmpi, nullptr, nullptr);
  k_hist<3><<<GH, 256, 0, stream>>>(tmpk, histg);
  k_scan<<<BATCH, 512, 0, stream>>>(histg);
  k_scatter<3><<<GH, 256, 0, stream>>>(tmpk, tmpi, histg, nullptr, nullptr, sortp, outq);
}

// Round 3
// 462.515 us; speedup vs baseline: 3.3960x; 2.6072x over previous
//
#include <hip/hip_runtime.h>

#define BATCH 256
#define PIX 65536

typedef short bf16x8 __attribute__((ext_vector_type(8)));
typedef float f32x4 __attribute__((ext_vector_type(4)));
typedef unsigned int u32;
typedef unsigned short u16;

__device__ __forceinline__ unsigned short bf16rne(float f) {
  unsigned u = __float_as_uint(f);
  u += 0x7FFFu + ((u >> 16) & 1u);
  return (unsigned short)(u >> 16);
}

__device__ __forceinline__ float tanh_fast(float x) {
  float e = __expf(2.0f * x);
  return 1.0f - 2.0f / (e + 1.0f);
}

// ---------------- x0 = concat(embed[labels], noise) ----------------
__global__ void k_build_x0(const float* __restrict__ noise, const int* __restrict__ labels,
                           const float* __restrict__ embed, float* __restrict__ x0) {
  int row = blockIdx.x, t = threadIdx.x;
  if (t < 110) {
    float v = (t < 10) ? embed[labels[row] * 10 + t] : noise[row * 100 + (t - 10)];
    x0[row * 110 + t] = v;
  }
}

// ---------------- small layer: h = x@W+b; BN(batch stats, eps=0.8); LeakyReLU(0.2)
__global__ __launch_bounds__(256) void k_layer(
    const float* __restrict__ xin, const float* __restrict__ W,
    const float* __restrict__ bias, const float* __restrict__ gam,
    const float* __restrict__ bet, float* __restrict__ xout,
    unsigned short* __restrict__ afrag, int K, int N) {
  int j = blockIdx.x, i = threadIdx.x;
  float a0 = 0.f, a1 = 0.f, a2 = 0.f, a3 = 0.f;
  int k = 0;
  for (; k + 4 <= K; k += 4) {
    a0 = fmaf(xin[i * K + k + 0], W[(k + 0) * N + j], a0);
    a1 = fmaf(xin[i * K + k + 1], W[(k + 1) * N + j], a1);
    a2 = fmaf(xin[i * K + k + 2], W[(k + 2) * N + j], a2);
    a3 = fmaf(xin[i * K + k + 3], W[(k + 3) * N + j], a3);
  }
  for (; k < K; ++k) a0 = fmaf(xin[i * K + k], W[k * N + j], a0);
  float h = a0 + a1 + a2 + a3 + bias[j];

  __shared__ float rs[256], rq[256];
  rs[i] = h; rq[i] = h * h;
  __syncthreads();
  for (int s = 128; s > 0; s >>= 1) {
    if (i < s) { rs[i] += rs[i + s]; rq[i] += rq[i + s]; }
    __syncthreads();
  }
  float mu = rs[0] * (1.0f / 256.0f);
  float var = rq[0] * (1.0f / 256.0f) - mu * mu;
  float y = (h - mu) * rsqrtf(var + 0.8f) * gam[j] + bet[j];
  y = (y >= 0.0f) ? y : 0.2f * y;
  if (xout) xout[i * N + j] = y;
  if (afrag) {
    int kc = j >> 5, kin = j & 31, g = kin >> 3, e = kin & 7;
    int mt = i >> 4, r = i & 15;
    afrag[(size_t)(((kc * 16 + mt) * 64) + (r + (g << 4))) * 8 + e] = bf16rne(y);
  }
}

// ---------------- GEMM5: img = tanh(x4 @ W5 + b5), bf16 MFMA 16x16x32 ----------------
__global__ __launch_bounds__(256) void k_gemm5(
    const unsigned short* __restrict__ A, const float* __restrict__ W5,
    const float* __restrict__ b5, float* __restrict__ img) {
  __shared__ unsigned short Bs[4096];
  const int n0 = blockIdx.x << 6;
  const int tid = threadIdx.x;
  const int w = tid >> 6, lane = tid & 63;
  f32x4 acc[4][4];
#pragma unroll
  for (int m = 0; m < 4; ++m)
#pragma unroll
    for (int n = 0; n < 4; ++n) acc[m][n] = (f32x4){0.f, 0.f, 0.f, 0.f};

  for (int cc = 0; cc < 16; ++cc) {
    __syncthreads();
#pragma unroll
    for (int half = 0; half < 2; ++half) {
      int kk = cc * 64 + half * 32 + w * 8;
      bf16x8 pk;
#pragma unroll
      for (int q = 0; q < 8; ++q) {
        float v = W5[(size_t)(kk + q) * PIX + n0 + lane];
        pk[q] = (short)bf16rne(v);
      }
      int dst = ((half * 4 + (lane >> 4)) * 64 + ((lane & 15) + (w << 4))) * 8;
      *(bf16x8*)&Bs[dst] = pk;
    }
    __syncthreads();
#pragma unroll
    for (int kcc = 0; kcc < 2; ++kcc) {
      int kc = cc * 2 + kcc;
      bf16x8 a[4], bv[4];
#pragma unroll
      for (int m = 0; m < 4; ++m)
        a[m] = *(const bf16x8*)&A[(size_t)((kc * 16 + (w * 4 + m)) * 64 + lane) * 8];
#pragma unroll
      for (int n = 0; n < 4; ++n)
        bv[n] = *(const bf16x8*)&Bs[((kcc * 4 + n) * 64 + lane) * 8];
#pragma unroll
      for (int m = 0; m < 4; ++m)
#pragma unroll
        for (int n = 0; n < 4; ++n)
          acc[m][n] = __builtin_amdgcn_mfma_f32_16x16x32_bf16(a[m], bv[n], acc[m][n], 0, 0, 0);
    }
  }
#pragma unroll
  for (int m = 0; m < 4; ++m) {
    int rb = (w << 6) + (m << 4) + ((lane >> 4) << 2);
#pragma unroll
    for (int n = 0; n < 4; ++n) {
      int col = n0 + (n << 4) + (lane & 15);
      float bb = b5[col];
#pragma unroll
      for (int r = 0; r < 4; ++r) {
        float h = acc[m][n][r] + bb;
        img[(size_t)(rb + r) * PIX + col] = tanh_fast(h);
      }
    }
  }
}

// ================= counting-sort STE-gray (16-bit fixed-point keys) =================
// Per row: 64K-bin histogram packed as 32768 u32 (two u16 fields) = 128KB LDS.
// u16-carry hazard (low field hitting 65536) can only corrupt the start of a
// provably-empty bin -> harmless.

// ---- kernel A: sorted p as u16 keys, via per-row histogram + run-length expand ----
__global__ __launch_bounds__(1024) void k_sortp(const float* __restrict__ rimg,
                                                u16* __restrict__ spk) {
  __shared__ u32 hist[32768];  // 128KB
  __shared__ u32 wtot[16];
  const int row = blockIdx.x, tid = threadIdx.x;
  const int wid = tid >> 6, lane = tid & 63;
  for (int i = tid; i < 32768; i += 1024) hist[i] = 0;
  __syncthreads();
  const float* src = rimg + (size_t)row * PIX;
#pragma unroll 8
  for (int s = 0; s < 64; ++s) {
    float f = src[s * 1024 + tid];
    u32 k = (u32)(f * 65536.0f);
    k = k > 65535u ? 65535u : k;
    atomicAdd(&hist[k >> 1], (k & 1) ? 0x10000u : 1u);
  }
  __syncthreads();
  // thread owns packed words [tid*32, tid*32+32) = bins [tid*64, tid*64+64)
  u32 cnt[32];
  u32 local = 0;
#pragma unroll
  for (int w = 0; w < 32; ++w) {
    u32 v = hist[tid * 32 + w];
    cnt[w] = v;
    local += (v & 0xFFFFu) + (v >> 16);
  }
  u32 sc = local;
#pragma unroll
  for (int o = 1; o < 64; o <<= 1) {
    u32 v = __shfl_up(sc, o);
    if (lane >= o) sc += v;
  }
  if (lane == 63) wtot[wid] = sc;
  __syncthreads();
  u32 run = sc - local;
  for (int ww = 0; ww < wid; ++ww) run += wtot[ww];
  u16* dst = spk + (size_t)row * PIX;
#pragma unroll
  for (int w = 0; w < 32; ++w) {
    u32 c0 = cnt[w] & 0xFFFFu, c1 = cnt[w] >> 16;
    u16 b0 = (u16)(tid * 64 + 2 * w), b1 = (u16)(tid * 64 + 2 * w + 1);
    for (u32 j = 0; j < c0; ++j) dst[run++] = b0;
    for (u32 j = 0; j < c1; ++j) dst[run++] = b1;
  }
}

// ---- kernel B: rank g per row (hist+scan+atomic fetch-add), gather sorted-p from LDS ----
__global__ __launch_bounds__(1024) void k_rankg(const float* __restrict__ img,
                                                const u16* __restrict__ spk,
                                                float* __restrict__ outq) {
  __shared__ u32 hist[32768];  // 128KB: counts -> starts -> reused as u16 sorted-p keys
  __shared__ u32 wtot[16];
  const int row = blockIdx.x, tid = threadIdx.x;
  const int wid = tid >> 6, lane = tid & 63;
  for (int i = tid; i < 32768; i += 1024) hist[i] = 0;
  __syncthreads();
  const float* g = img + (size_t)row * PIX;
  u32 kreg[32];  // 64 keys packed 2-per-reg (static indexing via full unroll)
#pragma unroll
  for (int s = 0; s < 64; ++s) {
    float f = g[s * 1024 + tid];
    u32 k = (u32)((f + 1.0f) * 32768.0f);
    k = k > 65535u ? 65535u : k;
    if (s & 1) kreg[s >> 1] |= k << 16;
    else kreg[s >> 1] = k;
    atomicAdd(&hist[k >> 1], (k & 1) ? 0x10000u : 1u);
  }
  __syncthreads();
  // exclusive scan over 64K bins -> packed starts in place
  u32 local = 0;
#pragma unroll
  for (int w = 0; w < 32; ++w) {
    u32 v = hist[tid * 32 + w];
    local += (v & 0xFFFFu) + (v >> 16);
  }
  u32 sc = local;
#pragma unroll
  for (int o = 1; o < 64; o <<= 1) {
    u32 v = __shfl_up(sc, o);
    if (lane >= o) sc += v;
  }
  if (lane == 63) wtot[wid] = sc;
  __syncthreads();
  u32 run = sc - local;
  for (int ww = 0; ww < wid; ++ww) run += wtot[ww];
#pragma unroll
  for (int w = 0; w < 32; ++w) {
    u32 v = hist[tid * 32 + w];
    u32 c0 = v & 0xFFFFu;
    hist[tid * 32 + w] = run | ((run + c0) << 16);
    run += c0 + (v >> 16);
  }
  __syncthreads();
  // rank assignment (atomic fetch-add on packed starts); overwrite kreg with ranks
#pragma unroll
  for (int s = 0; s < 64; ++s) {
    u32 k = (s & 1) ? (kreg[s >> 1] >> 16) : (kreg[s >> 1] & 0xFFFFu);
    u32 old = atomicAdd(&hist[k >> 1], (k & 1) ? 0x10000u : 1u);
    u32 r = (k & 1) ? (old >> 16) : (old & 0xFFFFu);
    if (s & 1) kreg[s >> 1] = (kreg[s >> 1] & 0x0000FFFFu) | (r << 16);
    else       kreg[s >> 1] = (kreg[s >> 1] & 0xFFFF0000u) | r;
  }
  __syncthreads();
  // stage sorted-p keys for this row into LDS (reuse hist buffer)
  {
    const u32* sp32 = (const u32*)(spk + (size_t)row * PIX);
    for (int i = tid; i < 32768; i += 1024) hist[i] = sp32[i];
  }
  __syncthreads();
  const u16* lsp = (const u16*)hist;
  float* dst = outq + (size_t)row * PIX;
#pragma unroll
  for (int s = 0; s < 64; ++s) {
    u32 r = (s & 1) ? (kreg[s >> 1] >> 16) : (kreg[s >> 1] & 0xFFFFu);
    dst[s * 1024 + tid] = ((float)lsp[r] + 0.5f) * (1.0f / 65536.0f);
  }
}

// ---------------- launch ----------------
extern "C" void kernel_launch(void* const* d_in, const int* in_sizes, int n_in,
                              void* d_out, int out_size, void* d_ws, size_t ws_size,
                              hipStream_t stream) {
  (void)in_sizes; (void)n_in; (void)out_size; (void)ws_size;
  const float* noise = (const float*)d_in[0];
  const float* rimg  = (const float*)d_in[1];
  const int* labels  = (const int*)d_in[2];
  const float* embed = (const float*)d_in[3];
  const float* W1 = (const float*)d_in[4];  const float* b1 = (const float*)d_in[5];
  const float* g1 = (const float*)d_in[6];  const float* be1 = (const float*)d_in[7];
  const float* W2 = (const float*)d_in[8];  const float* b2 = (const float*)d_in[9];
  const float* g2 = (const float*)d_in[10]; const float* be2 = (const float*)d_in[11];
  const float* W3 = (const float*)d_in[12]; const float* b3 = (const float*)d_in[13];
  const float* g3 = (const float*)d_in[14]; const float* be3 = (const float*)d_in[15];
  const float* W4 = (const float*)d_in[16]; const float* b4 = (const float*)d_in[17];
  const float* g4 = (const float*)d_in[18]; const float* be4 = (const float*)d_in[19];
  const float* W5 = (const float*)d_in[20]; const float* b5 = (const float*)d_in[21];

  float* outq = (float*)d_out;                        // img_quantized
  float* img  = (float*)d_out + (size_t)BATCH * PIX;  // img

  char* ws = (char*)d_ws;
  u16* spk = (u16*)ws;                                 // [0, 32M): sorted p keys per row
  char* small = ws + (size_t)32 * 1024 * 1024;
  float* x0 = (float*)small;
  float* x1 = (float*)(small + (1 << 20));
  float* x2 = (float*)(small + (2 << 20));
  float* x3 = (float*)(small + (3 << 20));
  float* x4f = (float*)(small + (4 << 20));
  unsigned short* x4b = (unsigned short*)(small + (5 << 20));

  k_build_x0<<<256, 128, 0, stream>>>(noise, labels, embed, x0);
  k_layer<<<128, 256, 0, stream>>>(x0, W1, b1, g1, be1, x1, nullptr, 110, 128);
  k_layer<<<256, 256, 0, stream>>>(x1, W2, b2, g2, be2, x2, nullptr, 128, 256);
  k_layer<<<512, 256, 0, stream>>>(x2, W3, b3, g3, be3, x3, nullptr, 256, 512);
  k_layer<<<1024, 256, 0, stream>>>(x3, W4, b4, g4, be4, x4f, x4b, 512, 1024);
  k_gemm5<<<1024, 256, 0, stream>>>(x4b, W5, b5, img);

  k_sortp<<<BATCH, 1024, 0, stream>>>(rimg, spk);
  k_rankg<<<BATCH, 1024, 0, stream>>>(img, spk, outq);
}

// Round 4
// 340.851 us; speedup vs baseline: 4.6082x; 1.3569x over previous
//
#include <hip/hip_runtime.h>

#define BATCH 256
#define PIX 65536

typedef short bf16x8 __attribute__((ext_vector_type(8)));
typedef float f32x4 __attribute__((ext_vector_type(4)));
typedef unsigned int u32;
typedef unsigned short u16;
typedef u32 u32x4 __attribute__((ext_vector_type(4)));

__device__ __forceinline__ unsigned short bf16rne(float f) {
  unsigned u = __float_as_uint(f);
  u += 0x7FFFu + ((u >> 16) & 1u);
  return (unsigned short)(u >> 16);
}

__device__ __forceinline__ float tanh_fast(float x) {
  float e = __expf(2.0f * x);
  return 1.0f - 2.0f / (e + 1.0f);
}

// ================= prep: W transposes (padded rows) + x0 build (packed) =================
// x0p [112/4][256][4] floats; W1t[128][112] W2t[256][128] W3t[512][256] W4t[1024][512]
#define E0 28672     // x0p elems (112*256)
#define E1 43008     // +W1t 128*112
#define E2 75776     // +W2t 256*128
#define E3 206848    // +W3t 512*256
#define E4 731136    // +W4t 1024*512

__global__ __launch_bounds__(256) void k_prep(
    const float* __restrict__ noise, const int* __restrict__ labels,
    const float* __restrict__ embed,
    const float* __restrict__ W1, const float* __restrict__ W2,
    const float* __restrict__ W3, const float* __restrict__ W4,
    float* __restrict__ x0p, float* __restrict__ W1t, float* __restrict__ W2t,
    float* __restrict__ W3t, float* __restrict__ W4t) {
  int idx = blockIdx.x * 256 + threadIdx.x;
  if (idx < E0) {
    int k = idx >> 8, i = idx & 255;
    float v = 0.f;
    if (k < 10) v = embed[labels[i] * 10 + k];
    else if (k < 110) v = noise[i * 100 + (k - 10)];
    x0p[((k >> 2) * 256 + i) * 4 + (k & 3)] = v;
  } else if (idx < E1) {
    int l = idx - E0; int j = l / 112, k = l - j * 112;
    W1t[l] = (k < 110) ? W1[k * 128 + j] : 0.f;
  } else if (idx < E2) {
    int l = idx - E1; int j = l >> 7, k = l & 127;
    W2t[l] = W2[k * 256 + j];
  } else if (idx < E3) {
    int l = idx - E2; int j = l >> 8, k = l & 255;
    W3t[l] = W3[k * 512 + j];
  } else {
    int l = idx - E3; int j = l >> 9, k = l & 511;
    W4t[l] = W4[k * 1024 + j];
  }
}

// ================= layer: h=x@W(+b); BN(batch, eps=0.8); LeakyReLU(0.2) =================
// xp: [KP/4][256][4]; Wt: [N][KP]; 8 features per block; thread = batch row.
template <int KP>
__global__ __launch_bounds__(256) void k_layer2(
    const float* __restrict__ xp, const float* __restrict__ Wt,
    const float* __restrict__ bias, const float* __restrict__ gam,
    const float* __restrict__ bet, float* __restrict__ yp,
    u16* __restrict__ afrag) {
  const int i = threadIdx.x;
  const int j0 = blockIdx.x * 8;
  const int wid = i >> 6, lane = i & 63;
  float acc[8];
#pragma unroll
  for (int f = 0; f < 8; ++f) acc[f] = 0.f;
  for (int k4 = 0; k4 < KP / 4; ++k4) {
    f32x4 xv = ((const f32x4*)xp)[k4 * 256 + i];
#pragma unroll
    for (int f = 0; f < 8; ++f) {
      f32x4 wv = *(const f32x4*)(Wt + (size_t)(j0 + f) * KP + k4 * 4);
      acc[f] = fmaf(xv[0], wv[0], acc[f]);
      acc[f] = fmaf(xv[1], wv[1], acc[f]);
      acc[f] = fmaf(xv[2], wv[2], acc[f]);
      acc[f] = fmaf(xv[3], wv[3], acc[f]);
    }
  }
  __shared__ float ssum[8][4], ssq[8][4];
  __shared__ float smu[8], srs[8];
#pragma unroll
  for (int f = 0; f < 8; ++f) {
    float h = acc[f] + bias[j0 + f];
    acc[f] = h;
    float s = h, q = h * h;
#pragma unroll
    for (int o = 32; o; o >>= 1) { s += __shfl_xor(s, o); q += __shfl_xor(q, o); }
    if (lane == 0) { ssum[f][wid] = s; ssq[f][wid] = q; }
  }
  __syncthreads();
  if (i < 8) {
    float s = ssum[i][0] + ssum[i][1] + ssum[i][2] + ssum[i][3];
    float q = ssq[i][0] + ssq[i][1] + ssq[i][2] + ssq[i][3];
    float mu = s * (1.0f / 256.0f);
    float var = q * (1.0f / 256.0f) - mu * mu;
    smu[i] = mu;
    srs[i] = rsqrtf(var + 0.8f) * gam[j0 + i];
  }
  __syncthreads();
#pragma unroll
  for (int f = 0; f < 8; ++f) {
    int j = j0 + f;
    float y = (acc[f] - smu[f]) * srs[f] + bet[j];
    y = (y >= 0.f) ? y : 0.2f * y;
    if (yp) yp[((j >> 2) * 256 + i) * 4 + (j & 3)] = y;
    if (afrag) {
      int kc = j >> 5, kin = j & 31, g = kin >> 3, e = kin & 7;
      int mt = i >> 4, r = i & 15;
      afrag[(size_t)(((kc * 16 + mt) * 64) + (r + (g << 4))) * 8 + e] = bf16rne(y);
    }
  }
}

// ---------------- GEMM5: img = tanh(x4 @ W5 + b5), bf16 MFMA, double-buffered ----------------
__global__ __launch_bounds__(256) void k_gemm5(
    const u16* __restrict__ A, const float* __restrict__ W5,
    const float* __restrict__ b5, float* __restrict__ img) {
  __shared__ unsigned short Bs[2][4096];
  const int n0 = blockIdx.x << 6;
  const int tid = threadIdx.x;
  const int w = tid >> 6, lane = tid & 63;
  f32x4 acc[4][4];
#pragma unroll
  for (int m = 0; m < 4; ++m)
#pragma unroll
    for (int n = 0; n < 4; ++n) acc[m][n] = (f32x4){0.f, 0.f, 0.f, 0.f};

  const int dst0 = (((lane >> 4)) * 64 + ((lane & 15) + (w << 4))) * 8;      // half 0
  const int dst1 = ((4 + (lane >> 4)) * 64 + ((lane & 15) + (w << 4))) * 8;  // half 1
  // prologue: stage cc=0 into buf 0
  {
#pragma unroll
    for (int half = 0; half < 2; ++half) {
      int kk = half * 32 + w * 8;
      bf16x8 pk;
#pragma unroll
      for (int q = 0; q < 8; ++q) pk[q] = (short)bf16rne(W5[(size_t)(kk + q) * PIX + n0 + lane]);
      *(bf16x8*)&Bs[0][half ? dst1 : dst0] = pk;
    }
  }
  for (int cc = 0; cc < 16; ++cc) {
    __syncthreads();
    float fv[16];
    if (cc < 15) {
#pragma unroll
      for (int half = 0; half < 2; ++half)
#pragma unroll
        for (int q = 0; q < 8; ++q)
          fv[half * 8 + q] = W5[(size_t)((cc + 1) * 64 + half * 32 + w * 8 + q) * PIX + n0 + lane];
    }
    const unsigned short* Bc = Bs[cc & 1];
#pragma unroll
    for (int kcc = 0; kcc < 2; ++kcc) {
      int kc = cc * 2 + kcc;
      bf16x8 a[4], bv[4];
#pragma unroll
      for (int m = 0; m < 4; ++m)
        a[m] = *(const bf16x8*)&A[(size_t)((kc * 16 + (w * 4 + m)) * 64 + lane) * 8];
#pragma unroll
      for (int n = 0; n < 4; ++n)
        bv[n] = *(const bf16x8*)&Bc[((kcc * 4 + n) * 64 + lane) * 8];
#pragma unroll
      for (int m = 0; m < 4; ++m)
#pragma unroll
        for (int n = 0; n < 4; ++n)
          acc[m][n] = __builtin_amdgcn_mfma_f32_16x16x32_bf16(a[m], bv[n], acc[m][n], 0, 0, 0);
    }
    if (cc < 15) {
      unsigned short* Bn = Bs[(cc + 1) & 1];
#pragma unroll
      for (int half = 0; half < 2; ++half) {
        bf16x8 pk;
#pragma unroll
        for (int q = 0; q < 8; ++q) pk[q] = (short)bf16rne(fv[half * 8 + q]);
        *(bf16x8*)&Bn[half ? dst1 : dst0] = pk;
      }
    }
  }
#pragma unroll
  for (int m = 0; m < 4; ++m) {
    int rb = (w << 6) + (m << 4) + ((lane >> 4) << 2);
#pragma unroll
    for (int n = 0; n < 4; ++n) {
      int col = n0 + (n << 4) + (lane & 15);
      float bb = b5[col];
#pragma unroll
      for (int r = 0; r < 4; ++r) {
        float h = acc[m][n][r] + bb;
        img[(size_t)(rb + r) * PIX + col] = tanh_fast(h);
      }
    }
  }
}

// ================= counting-sort STE-gray (16-bit fixed-point keys) =================

// ---- kernel A: sorted p keys via per-row histogram + LDS expansion + coalesced write ----
__global__ __launch_bounds__(1024) void k_sortp(const float* __restrict__ rimg,
                                                u16* __restrict__ spk) {
  __shared__ u32 hist[32768];  // 128KB: packed 2xu16 counts -> reused as u16 skey[65536]
  __shared__ u32 wtot[16];
  const int row = blockIdx.x, tid = threadIdx.x;
  const int wid = tid >> 6, lane = tid & 63;
  for (int i = tid; i < 32768; i += 1024) hist[i] = 0;
  __syncthreads();
  const f32x4* src = (const f32x4*)(rimg + (size_t)row * PIX);
#pragma unroll
  for (int s4 = 0; s4 < 16; ++s4) {
    f32x4 v = src[s4 * 1024 + tid];
#pragma unroll
    for (int e = 0; e < 4; ++e) {
      u32 k = (u32)(v[e] * 65536.0f);
      k = k > 65535u ? 65535u : k;
      atomicAdd(&hist[k >> 1], (k & 1) ? 0x10000u : 1u);
    }
  }
  __syncthreads();
  u32 cnt[32];
  u32 local = 0;
#pragma unroll
  for (int w = 0; w < 32; ++w) {
    u32 v = hist[tid * 32 + w];
    cnt[w] = v;
    local += (v & 0xFFFFu) + (v >> 16);
  }
  u32 sc = local;
#pragma unroll
  for (int o = 1; o < 64; o <<= 1) {
    u32 v = __shfl_up(sc, o);
    if (lane >= o) sc += v;
  }
  if (lane == 63) wtot[wid] = sc;
  __syncthreads();  // also: all hist reads complete beyond this point
  u32 run = sc - local;
  for (int ww = 0; ww < wid; ++ww) run += wtot[ww];
  // expand into LDS (reuse hist region as u16 keys)
  u16* skey = (u16*)hist;
#pragma unroll
  for (int w = 0; w < 32; ++w) {
    u32 c0 = cnt[w] & 0xFFFFu, c1 = cnt[w] >> 16;
    u16 b0 = (u16)(tid * 64 + 2 * w), b1 = (u16)(tid * 64 + 2 * w + 1);
    for (u32 j = 0; j < c0; ++j) skey[run++] = b0;
    for (u32 j = 0; j < c1; ++j) skey[run++] = b1;
  }
  __syncthreads();
  u32x4* dst = (u32x4*)(spk + (size_t)row * PIX);
  const u32x4* s4p = (const u32x4*)hist;
#pragma unroll
  for (int t = 0; t < 8; ++t) dst[t * 1024 + tid] = s4p[t * 1024 + tid];
}

// ---- kernel B: rank g per row (hist+scan+atomic fetch-add), gather sorted-p from LDS ----
__global__ __launch_bounds__(1024) void k_rankg(const float* __restrict__ img,
                                                const u16* __restrict__ spk,
                                                float* __restrict__ outq) {
  __shared__ u32 hist[32768];  // counts -> starts -> reused as u16 sorted-p keys
  __shared__ u32 wtot[16];
  const int row = blockIdx.x, tid = threadIdx.x;
  const int wid = tid >> 6, lane = tid & 63;
  for (int i = tid; i < 32768; i += 1024) hist[i] = 0;
  __syncthreads();
  const float* g = img + (size_t)row * PIX;
  u32 kreg[32];
#pragma unroll
  for (int s = 0; s < 64; ++s) {
    float f = g[s * 1024 + tid];
    u32 k = (u32)((f + 1.0f) * 32768.0f);
    k = k > 65535u ? 65535u : k;
    if (s & 1) kreg[s >> 1] |= k << 16;
    else kreg[s >> 1] = k;
    atomicAdd(&hist[k >> 1], (k & 1) ? 0x10000u : 1u);
  }
  __syncthreads();
  u32 local = 0;
#pragma unroll
  for (int w = 0; w < 32; ++w) {
    u32 v = hist[tid * 32 + w];
    local += (v & 0xFFFFu) + (v >> 16);
  }
  u32 sc = local;
#pragma unroll
  for (int o = 1; o < 64; o <<= 1) {
    u32 v = __shfl_up(sc, o);
    if (lane >= o) sc += v;
  }
  if (lane == 63) wtot[wid] = sc;
  __syncthreads();
  u32 run = sc - local;
  for (int ww = 0; ww < wid; ++ww) run += wtot[ww];
#pragma unroll
  for (int w = 0; w < 32; ++w) {
    u32 v = hist[tid * 32 + w];
    u32 c0 = v & 0xFFFFu;
    hist[tid * 32 + w] = run | ((run + c0) << 16);
    run += c0 + (v >> 16);
  }
  __syncthreads();
#pragma unroll
  for (int s = 0; s < 64; ++s) {
    u32 k = (s & 1) ? (kreg[s >> 1] >> 16) : (kreg[s >> 1] & 0xFFFFu);
    u32 old = atomicAdd(&hist[k >> 1], (k & 1) ? 0x10000u : 1u);
    u32 r = (k & 1) ? (old >> 16) : (old & 0xFFFFu);
    if (s & 1) kreg[s >> 1] = (kreg[s >> 1] & 0x0000FFFFu) | (r << 16);
    else       kreg[s >> 1] = (kreg[s >> 1] & 0xFFFF0000u) | r;
  }
  __syncthreads();
  {
    const u32* sp32 = (const u32*)(spk + (size_t)row * PIX);
    for (int i = tid; i < 32768; i += 1024) hist[i] = sp32[i];
  }
  __syncthreads();
  const u16* lsp = (const u16*)hist;
  float* dst = outq + (size_t)row * PIX;
#pragma unroll
  for (int s = 0; s < 64; ++s) {
    u32 r = (s & 1) ? (kreg[s >> 1] >> 16) : (kreg[s >> 1] & 0xFFFFu);
    dst[s * 1024 + tid] = ((float)lsp[r] + 0.5f) * (1.0f / 65536.0f);
  }
}

// ---------------- launch ----------------
extern "C" void kernel_launch(void* const* d_in, const int* in_sizes, int n_in,
                              void* d_out, int out_size, void* d_ws, size_t ws_size,
                              hipStream_t stream) {
  (void)in_sizes; (void)n_in; (void)out_size; (void)ws_size;
  const float* noise = (const float*)d_in[0];
  const float* rimg  = (const float*)d_in[1];
  const int* labels  = (const int*)d_in[2];
  const float* embed = (const float*)d_in[3];
  const float* W1 = (const float*)d_in[4];  const float* b1 = (const float*)d_in[5];
  const float* g1 = (const float*)d_in[6];  const float* be1 = (const float*)d_in[7];
  const float* W2 = (const float*)d_in[8];  const float* b2 = (const float*)d_in[9];
  const float* g2 = (const float*)d_in[10]; const float* be2 = (const float*)d_in[11];
  const float* W3 = (const float*)d_in[12]; const float* b3 = (const float*)d_in[13];
  const float* g3 = (const float*)d_in[14]; const float* be3 = (const float*)d_in[15];
  const float* W4 = (const float*)d_in[16]; const float* b4 = (const float*)d_in[17];
  const float* g4 = (const float*)d_in[18]; const float* be4 = (const float*)d_in[19];
  const float* W5 = (const float*)d_in[20]; const float* b5 = (const float*)d_in[21];

  float* outq = (float*)d_out;                        // img_quantized
  float* img  = (float*)d_out + (size_t)BATCH * PIX;  // img

  char* ws = (char*)d_ws;
  u16* spk = (u16*)ws;  // [0, 32M): sorted p keys per row
  float* small = (float*)(ws + (size_t)32 * 1024 * 1024);
  float* x0p = small;            // 28672
  float* W1t = small + 258048;   // 14336
  float* W2t = small + 272384;   // 32768
  float* W3t = small + 305152;   // 131072
  float* W4t = small + 436224;   // 524288
  float* x1p = small + 28672;    // 32768
  float* x2p = small + 61440;    // 65536
  float* x3p = small + 126976;   // 131072
  u16* afrag = (u16*)(small + 960512);  // 256*1024 u16

  k_prep<<<E4 / 256, 256, 0, stream>>>(noise, labels, embed, W1, W2, W3, W4,
                                       x0p, W1t, W2t, W3t, W4t);
  k_layer2<112><<<16, 256, 0, stream>>>(x0p, W1t, b1, g1, be1, x1p, nullptr);
  k_layer2<128><<<32, 256, 0, stream>>>(x1p, W2t, b2, g2, be2, x2p, nullptr);
  k_layer2<256><<<64, 256, 0, stream>>>(x2p, W3t, b3, g3, be3, x3p, nullptr);
  k_layer2<512><<<128, 256, 0, stream>>>(x3p, W4t, b4, g4, be4, nullptr, afrag);
  k_gemm5<<<1024, 256, 0, stream>>>(afrag, W5, b5, img);

  k_sortp<<<BATCH, 1024, 0, stream>>>(rimg, spk);
  k_rankg<<<BATCH, 1024, 0, stream>>>(img, spk, outq);
}

// Round 6
// 326.735 us; speedup vs baseline: 4.8073x; 1.0432x over previous
//
#include <hip/hip_runtime.h>

#define BATCH 256
#define PIX 65536

typedef short bf16x8 __attribute__((ext_vector_type(8)));
typedef float f32x4 __attribute__((ext_vector_type(4)));
typedef unsigned int u32;
typedef unsigned short u16;
typedef u32 u32x4 __attribute__((ext_vector_type(4)));

__device__ __forceinline__ unsigned short bf16rne(float f) {
  unsigned u = __float_as_uint(f);
  u += 0x7FFFu + ((u >> 16) & 1u);
  return (unsigned short)(u >> 16);
}

__device__ __forceinline__ float tanh_fast(float x) {
  float e = __expf(2.0f * x);
  return 1.0f - 2.0f / (e + 1.0f);
}

// swizzled physical index for packed histogram word W (bijective per 32-word segment)
__device__ __forceinline__ u32 hswz(u32 W) {
  return (W & ~31u) | (((W & 31u) + (W >> 5)) & 31u);
}

// ================= prep: W transposes (padded rows) + x0 build (packed) =================
#define E0 28672
#define E1 43008
#define E2 75776
#define E3 206848
#define E4 731136

__global__ __launch_bounds__(256) void k_prep(
    const float* __restrict__ noise, const int* __restrict__ labels,
    const float* __restrict__ embed,
    const float* __restrict__ W1, const float* __restrict__ W2,
    const float* __restrict__ W3, const float* __restrict__ W4,
    float* __restrict__ x0p, float* __restrict__ W1t, float* __restrict__ W2t,
    float* __restrict__ W3t, float* __restrict__ W4t) {
  int idx = blockIdx.x * 256 + threadIdx.x;
  if (idx < E0) {
    int k = idx >> 8, i = idx & 255;
    float v = 0.f;
    if (k < 10) v = embed[labels[i] * 10 + k];
    else if (k < 110) v = noise[i * 100 + (k - 10)];
    x0p[((k >> 2) * 256 + i) * 4 + (k & 3)] = v;
  } else if (idx < E1) {
    int l = idx - E0; int j = l / 112, k = l - j * 112;
    W1t[l] = (k < 110) ? W1[k * 128 + j] : 0.f;
  } else if (idx < E2) {
    int l = idx - E1; int j = l >> 7, k = l & 127;
    W2t[l] = W2[k * 256 + j];
  } else if (idx < E3) {
    int l = idx - E2; int j = l >> 8, k = l & 255;
    W3t[l] = W3[k * 512 + j];
  } else {
    int l = idx - E3; int j = l >> 9, k = l & 511;
    W4t[l] = W4[k * 1024 + j];
  }
}

// ================= layer: h=x@W(+b); BN(batch, eps=0.8); LeakyReLU(0.2) =================
template <int KP>
__global__ __launch_bounds__(256) void k_layer2(
    const float* __restrict__ xp, const float* __restrict__ Wt,
    const float* __restrict__ bias, const float* __restrict__ gam,
    const float* __restrict__ bet, float* __restrict__ yp,
    u16* __restrict__ afrag) {
  const int i = threadIdx.x;
  const int j0 = blockIdx.x * 8;
  const int wid = i >> 6, lane = i & 63;
  float acc[8];
#pragma unroll
  for (int f = 0; f < 8; ++f) acc[f] = 0.f;
  for (int k4 = 0; k4 < KP / 4; ++k4) {
    f32x4 xv = ((const f32x4*)xp)[k4 * 256 + i];
#pragma unroll
    for (int f = 0; f < 8; ++f) {
      f32x4 wv = *(const f32x4*)(Wt + (size_t)(j0 + f) * KP + k4 * 4);
      acc[f] = fmaf(xv[0], wv[0], acc[f]);
      acc[f] = fmaf(xv[1], wv[1], acc[f]);
      acc[f] = fmaf(xv[2], wv[2], acc[f]);
      acc[f] = fmaf(xv[3], wv[3], acc[f]);
    }
  }
  __shared__ float ssum[8][4], ssq[8][4];
  __shared__ float smu[8], srs[8];
#pragma unroll
  for (int f = 0; f < 8; ++f) {
    float h = acc[f] + bias[j0 + f];
    acc[f] = h;
    float s = h, q = h * h;
#pragma unroll
    for (int o = 32; o; o >>= 1) { s += __shfl_xor(s, o); q += __shfl_xor(q, o); }
    if (lane == 0) { ssum[f][wid] = s; ssq[f][wid] = q; }
  }
  __syncthreads();
  if (i < 8) {
    float s = ssum[i][0] + ssum[i][1] + ssum[i][2] + ssum[i][3];
    float q = ssq[i][0] + ssq[i][1] + ssq[i][2] + ssq[i][3];
    float mu = s * (1.0f / 256.0f);
    float var = q * (1.0f / 256.0f) - mu * mu;
    smu[i] = mu;
    srs[i] = rsqrtf(var + 0.8f) * gam[j0 + i];
  }
  __syncthreads();
#pragma unroll
  for (int f = 0; f < 8; ++f) {
    int j = j0 + f;
    float y = (acc[f] - smu[f]) * srs[f] + bet[j];
    y = (y >= 0.f) ? y : 0.2f * y;
    if (yp) yp[((j >> 2) * 256 + i) * 4 + (j & 3)] = y;
    if (afrag) {
      int kc = j >> 5, kin = j & 31, g = kin >> 3, e = kin & 7;
      int mt = i >> 4, r = i & 15;
      afrag[(size_t)(((kc * 16 + mt) * 64) + (r + (g << 4))) * 8 + e] = bf16rne(y);
    }
  }
}

// ---------------- GEMM5: img = tanh(x4 @ W5 + b5), bf16 MFMA, double-buffered ----------------
__global__ __launch_bounds__(256) void k_gemm5(
    const u16* __restrict__ A, const float* __restrict__ W5,
    const float* __restrict__ b5, float* __restrict__ img) {
  __shared__ unsigned short Bs[2][4096];
  const int n0 = blockIdx.x << 6;
  const int tid = threadIdx.x;
  const int w = tid >> 6, lane = tid & 63;
  f32x4 acc[4][4];
#pragma unroll
  for (int m = 0; m < 4; ++m)
#pragma unroll
    for (int n = 0; n < 4; ++n) acc[m][n] = (f32x4){0.f, 0.f, 0.f, 0.f};

  const int dst0 = (((lane >> 4)) * 64 + ((lane & 15) + (w << 4))) * 8;
  const int dst1 = ((4 + (lane >> 4)) * 64 + ((lane & 15) + (w << 4))) * 8;
  {
#pragma unroll
    for (int half = 0; half < 2; ++half) {
      int kk = half * 32 + w * 8;
      bf16x8 pk;
#pragma unroll
      for (int q = 0; q < 8; ++q) pk[q] = (short)bf16rne(W5[(size_t)(kk + q) * PIX + n0 + lane]);
      *(bf16x8*)&Bs[0][half ? dst1 : dst0] = pk;
    }
  }
  for (int cc = 0; cc < 16; ++cc) {
    __syncthreads();
    float fv[16];
    if (cc < 15) {
#pragma unroll
      for (int half = 0; half < 2; ++half)
#pragma unroll
        for (int q = 0; q < 8; ++q)
          fv[half * 8 + q] = W5[(size_t)((cc + 1) * 64 + half * 32 + w * 8 + q) * PIX + n0 + lane];
    }
    const unsigned short* Bc = Bs[cc & 1];
#pragma unroll
    for (int kcc = 0; kcc < 2; ++kcc) {
      int kc = cc * 2 + kcc;
      bf16x8 a[4], bv[4];
#pragma unroll
      for (int m = 0; m < 4; ++m)
        a[m] = *(const bf16x8*)&A[(size_t)((kc * 16 + (w * 4 + m)) * 64 + lane) * 8];
#pragma unroll
      for (int n = 0; n < 4; ++n)
        bv[n] = *(const bf16x8*)&Bc[((kcc * 4 + n) * 64 + lane) * 8];
#pragma unroll
      for (int m = 0; m < 4; ++m)
#pragma unroll
        for (int n = 0; n < 4; ++n)
          acc[m][n] = __builtin_amdgcn_mfma_f32_16x16x32_bf16(a[m], bv[n], acc[m][n], 0, 0, 0);
    }
    if (cc < 15) {
      unsigned short* Bn = Bs[(cc + 1) & 1];
#pragma unroll
      for (int half = 0; half < 2; ++half) {
        bf16x8 pk;
#pragma unroll
        for (int q = 0; q < 8; ++q) pk[q] = (short)bf16rne(fv[half * 8 + q]);
        *(bf16x8*)&Bn[half ? dst1 : dst0] = pk;
      }
    }
  }
#pragma unroll
  for (int m = 0; m < 4; ++m) {
    int rb = (w << 6) + (m << 4) + ((lane >> 4) << 2);
#pragma unroll
    for (int n = 0; n < 4; ++n) {
      int col = n0 + (n << 4) + (lane & 15);
      float bb = b5[col];
#pragma unroll
      for (int r = 0; r < 4; ++r) {
        float h = acc[m][n][r] + bb;
        img[(size_t)(rb + r) * PIX + col] = tanh_fast(h);
      }
    }
  }
}

// ================= fused STE-gray: rank(g) + counting-sort(p) + gather, one row/block ========
__global__ __launch_bounds__(1024) void k_ste(const float* __restrict__ img,
                                              const float* __restrict__ rimg,
                                              float* __restrict__ outq) {
  __shared__ u32 hist[32768];   // 128KB packed 2xu16; reused: g-hist/starts -> p-hist -> skey u16[65536]
  __shared__ u32 tbase[1024];   // 4KB per-thread p run bases
  __shared__ u32 wtot[16];
  const int row = blockIdx.x, tid = threadIdx.x;
  const int wid = tid >> 6, lane = tid & 63;

  // ---- phase 1: zero + g-keys + g-hist ----
  // element index for kreg slot s (= s4*4+e): (s4*1024+tid)*4 + e
  for (int i = tid; i < 32768; i += 1024) hist[i] = 0;
  __syncthreads();
  const f32x4* g4 = (const f32x4*)(img + (size_t)row * PIX);
  u32 kreg[32];
#pragma unroll
  for (int s4 = 0; s4 < 16; ++s4) {
    f32x4 v = g4[s4 * 1024 + tid];
#pragma unroll
    for (int e = 0; e < 4; ++e) {
      int s = s4 * 4 + e;
      u32 k = (u32)((v[e] + 1.0f) * 32768.0f);
      k = k > 65535u ? 65535u : k;
      if (s & 1) kreg[s >> 1] |= k << 16;
      else kreg[s >> 1] = k;
      atomicAdd(&hist[hswz(k >> 1)], (k & 1) ? 0x10000u : 1u);
    }
  }
  __syncthreads();
  // ---- phase 2: scan g-hist -> packed starts in place ----
  {
    u32 local = 0;
#pragma unroll
    for (int w = 0; w < 32; ++w) {
      u32 v = hist[tid * 32 + ((w + tid) & 31)];
      local += (v & 0xFFFFu) + (v >> 16);
    }
    u32 sc = local;
#pragma unroll
    for (int o = 1; o < 64; o <<= 1) {
      u32 x = __shfl_up(sc, o);
      if (lane >= o) sc += x;
    }
    if (lane == 63) wtot[wid] = sc;
    __syncthreads();
    u32 run = sc - local;
    for (int ww = 0; ww < wid; ++ww) run += wtot[ww];
#pragma unroll
    for (int w = 0; w < 32; ++w) {
      u32 pi = tid * 32 + ((w + tid) & 31);
      u32 v = hist[pi];
      u32 c0 = v & 0xFFFFu;
      hist[pi] = (run & 0xFFFFu) | ((run + c0) << 16);
      run += c0 + (v >> 16);
    }
  }
  __syncthreads();
  // ---- phase 3: assign ranks (kreg: keys -> ranks) ----
#pragma unroll
  for (int s = 0; s < 64; ++s) {
    u32 k = (s & 1) ? (kreg[s >> 1] >> 16) : (kreg[s >> 1] & 0xFFFFu);
    u32 old = atomicAdd(&hist[hswz(k >> 1)], (k & 1) ? 0x10000u : 1u);
    u32 r = (k & 1) ? (old >> 16) : (old & 0xFFFFu);
    if (s & 1) kreg[s >> 1] = (kreg[s >> 1] & 0x0000FFFFu) | (r << 16);
    else       kreg[s >> 1] = (kreg[s >> 1] & 0xFFFF0000u) | r;
  }
  __syncthreads();
  // ---- phase 4: zero + p-hist ----
  for (int i = tid; i < 32768; i += 1024) hist[i] = 0;
  __syncthreads();
  const f32x4* p4 = (const f32x4*)(rimg + (size_t)row * PIX);
#pragma unroll
  for (int s4 = 0; s4 < 16; ++s4) {
    f32x4 v = p4[s4 * 1024 + tid];
#pragma unroll
    for (int e = 0; e < 4; ++e) {
      u32 k = (u32)(v[e] * 65536.0f);
      k = k > 65535u ? 65535u : k;
      atomicAdd(&hist[hswz(k >> 1)], (k & 1) ? 0x10000u : 1u);
    }
  }
  __syncthreads();
  // ---- phase 5: scan p-hist -> tbase (counts stay intact) ----
  {
    u32 local = 0;
#pragma unroll
    for (int w = 0; w < 32; ++w) {
      u32 v = hist[tid * 32 + ((w + tid) & 31)];
      local += (v & 0xFFFFu) + (v >> 16);
    }
    u32 sc = local;
#pragma unroll
    for (int o = 1; o < 64; o <<= 1) {
      u32 x = __shfl_up(sc, o);
      if (lane >= o) sc += x;
    }
    if (lane == 63) wtot[wid] = sc;
    __syncthreads();
    u32 run = sc - local;
    for (int ww = 0; ww < wid; ++ww) run += wtot[ww];
    tbase[tid] = run;
  }
  // ---- phase 6: pre-read counts for wave-coop expansion (c16, static-indexed) ----
  u32 c16[32];
#pragma unroll
  for (int s = 0; s < 64; ++s) {
    int t = wid * 64 + s;
    u32 vw = hist[t * 32 + ((((u32)lane >> 1) + t) & 31)];
    u32 c = (lane & 1) ? (vw >> 16) : (vw & 0xFFFFu);
    if (s & 1) c16[s >> 1] |= c << 16;
    else c16[s >> 1] = c;
  }
  __syncthreads();  // all count reads + tbase visible before any skey write
  // ---- phase 7: wave-cooperative expansion into skey (linear u16, lanes interleave) ----
  u16* skey = (u16*)hist;
#pragma unroll
  for (int s = 0; s < 64; ++s) {
    int t = wid * 64 + s;
    u32 c = (s & 1) ? (c16[s >> 1] >> 16) : (c16[s >> 1] & 0xFFFFu);
    u32 o = c;
#pragma unroll
    for (int off = 1; off < 64; off <<= 1) {
      u32 x = __shfl_up(o, off);
      if (lane >= off) o += x;
    }
    u32 pos = tbase[t] + o - c;
    u16 key = (u16)(t * 64 + lane);
    for (u32 j = 0; j < c; ++j) skey[pos + j] = key;
  }
  __syncthreads();
  // ---- phase 8: gather sorted-p by rank, write out (mapping matches phase-1 load) ----
  f32x4* dst4 = (f32x4*)(outq + (size_t)row * PIX);
#pragma unroll
  for (int s4 = 0; s4 < 16; ++s4) {
    f32x4 o;
#pragma unroll
    for (int e = 0; e < 4; ++e) {
      int s = s4 * 4 + e;
      u32 r = (s & 1) ? (kreg[s >> 1] >> 16) : (kreg[s >> 1] & 0xFFFFu);
      o[e] = ((float)skey[r] + 0.5f) * (1.0f / 65536.0f);
    }
    dst4[s4 * 1024 + tid] = o;
  }
}

// ---------------- launch ----------------
extern "C" void kernel_launch(void* const* d_in, const int* in_sizes, int n_in,
                              void* d_out, int out_size, void* d_ws, size_t ws_size,
                              hipStream_t stream) {
  (void)in_sizes; (void)n_in; (void)out_size; (void)ws_size;
  const float* noise = (const float*)d_in[0];
  const float* rimg  = (const float*)d_in[1];
  const int* labels  = (const int*)d_in[2];
  const float* embed = (const float*)d_in[3];
  const float* W1 = (const float*)d_in[4];  const float* b1 = (const float*)d_in[5];
  const float* g1 = (const float*)d_in[6];  const float* be1 = (const float*)d_in[7];
  const float* W2 = (const float*)d_in[8];  const float* b2 = (const float*)d_in[9];
  const float* g2 = (const float*)d_in[10]; const float* be2 = (const float*)d_in[11];
  const float* W3 = (const float*)d_in[12]; const float* b3 = (const float*)d_in[13];
  const float* g3 = (const float*)d_in[14]; const float* be3 = (const float*)d_in[15];
  const float* W4 = (const float*)d_in[16]; const float* b4 = (const float*)d_in[17];
  const float* g4 = (const float*)d_in[18]; const float* be4 = (const float*)d_in[19];
  const float* W5 = (const float*)d_in[20]; const float* b5 = (const float*)d_in[21];

  float* outq = (float*)d_out;                        // img_quantized
  float* img  = (float*)d_out + (size_t)BATCH * PIX;  // img

  float* small = (float*)d_ws;
  float* x0p = small;            // 28672
  float* x1p = small + 28672;    // 32768
  float* x2p = small + 61440;    // 65536
  float* x3p = small + 126976;   // 131072
  float* W1t = small + 258048;   // 14336
  float* W2t = small + 272384;   // 32768
  float* W3t = small + 305152;   // 131072
  float* W4t = small + 436224;   // 524288
  u16* afrag = (u16*)(small + 960512);  // 256*1024 u16

  k_prep<<<E4 / 256, 256, 0, stream>>>(noise, labels, embed, W1, W2, W3, W4,
                                       x0p, W1t, W2t, W3t, W4t);
  k_layer2<112><<<16, 256, 0, stream>>>(x0p, W1t, b1, g1, be1, x1p, nullptr);
  k_layer2<128><<<32, 256, 0, stream>>>(x1p, W2t, b2, g2, be2, x2p, nullptr);
  k_layer2<256><<<64, 256, 0, stream>>>(x2p, W3t, b3, g3, be3, x3p, nullptr);
  k_layer2<512><<<128, 256, 0, stream>>>(x3p, W4t, b4, g4, be4, nullptr, afrag);
  k_gemm5<<<1024, 256, 0, stream>>>(afrag, W5, b5, img);
  k_ste<<<BATCH, 1024, 0, stream>>>(img, rimg, outq);
}